// Round 8
// baseline (217.970 us; speedup 1.0000x reference)
//
#include <hip/hip_runtime.h>
#include <hip/hip_bf16.h>

#define B_ 32
#define N_ 512
#define H_ 128

typedef float f32x4 __attribute__((ext_vector_type(4)));
typedef short short8 __attribute__((ext_vector_type(8)));
typedef short short4v __attribute__((ext_vector_type(4)));

static __device__ __forceinline__ float bf2f(unsigned short u) {
  union { unsigned int ui; float f; } x;
  x.ui = ((unsigned int)u) << 16;
  return x.f;
}
static __device__ __forceinline__ unsigned short f2bf(float f) {
  __hip_bfloat16 h = __float2bfloat16(f);
  return *reinterpret_cast<unsigned short*>(&h);
}

// -------------------------------------------------------------------------
// Kernel 1: h[b,n,d] = silu(LN(s[b,n,:] @ W1[d,:] + b1[d]))
// stored TRANSPOSED bf16 into ws:  h_t[b][d][n]
// (unchanged — not the bottleneck per rocprof)
// -------------------------------------------------------------------------
__global__ __launch_bounds__(256) void lin_ln_silu_kernel(
    const float* __restrict__ s, const float* __restrict__ W1,
    const float* __restrict__ b1, unsigned short* __restrict__ h_t) {
  __shared__ float s_sh[32 * 132];            // [n][k] fp32, pad 132
  __shared__ unsigned short w_sh[128 * 132];  // [d][k] bf16, pad 132
  __shared__ unsigned short ht_sh[128 * 40];  // [d][n] bf16, pad 40
  const int t = threadIdx.x;
  const int b = blockIdx.y;
  const int n0 = blockIdx.x * 32;

#pragma unroll
  for (int r = 0; r < 16; ++r) {
    int q = t + 256 * r;
    int d = q >> 5, part = q & 31;
    float4 v = *reinterpret_cast<const float4*>(W1 + d * H_ + part * 4);
    short4v w;
    w.x = (short)f2bf(v.x); w.y = (short)f2bf(v.y);
    w.z = (short)f2bf(v.z); w.w = (short)f2bf(v.w);
    *reinterpret_cast<short4v*>(&w_sh[d * 132 + part * 4]) = w;
  }
#pragma unroll
  for (int r = 0; r < 4; ++r) {
    int q = t + 256 * r;
    int n = q >> 5, part = q & 31;
    float4 v = *reinterpret_cast<const float4*>(
        s + ((size_t)b * N_ + n0 + n) * H_ + part * 4);
    *reinterpret_cast<float4*>(&s_sh[n * 132 + part * 4]) = v;
  }
  __syncthreads();

  const int a = t & 15;
  const int g = t >> 4;
  float acc[2][8];
#pragma unroll
  for (int nn = 0; nn < 2; ++nn)
#pragma unroll
    for (int dd = 0; dd < 8; ++dd) acc[nn][dd] = 0.f;

  float bias[8];
#pragma unroll
  for (int dd = 0; dd < 8; ++dd) bias[dd] = b1[dd * 16 + a];

  for (int k = 0; k < 128; k += 4) {
    float wf[8][4];
#pragma unroll
    for (int dd = 0; dd < 8; ++dd) {
      short4v wv =
          *reinterpret_cast<const short4v*>(&w_sh[(dd * 16 + a) * 132 + k]);
      wf[dd][0] = bf2f((unsigned short)wv.x);
      wf[dd][1] = bf2f((unsigned short)wv.y);
      wf[dd][2] = bf2f((unsigned short)wv.z);
      wf[dd][3] = bf2f((unsigned short)wv.w);
    }
#pragma unroll
    for (int nn = 0; nn < 2; ++nn) {
      float4 sv =
          *reinterpret_cast<const float4*>(&s_sh[(nn * 16 + g) * 132 + k]);
#pragma unroll
      for (int dd = 0; dd < 8; ++dd) {
        acc[nn][dd] += sv.x * wf[dd][0] + sv.y * wf[dd][1] +
                       sv.z * wf[dd][2] + sv.w * wf[dd][3];
      }
    }
  }

#pragma unroll
  for (int nn = 0; nn < 2; ++nn) {
    float s1 = 0.f, s2 = 0.f;
#pragma unroll
    for (int dd = 0; dd < 8; ++dd) {
      float x = acc[nn][dd] + bias[dd];
      acc[nn][dd] = x;
      s1 += x;
      s2 += x * x;
    }
#pragma unroll
    for (int off = 8; off >= 1; off >>= 1) {
      s1 += __shfl_xor(s1, off);
      s2 += __shfl_xor(s2, off);
    }
    float mean = s1 * (1.f / 128.f);
    float var = s2 * (1.f / 128.f) - mean * mean;
    float rs = rsqrtf(var + 1e-5f);
#pragma unroll
    for (int dd = 0; dd < 8; ++dd) {
      float x = (acc[nn][dd] - mean) * rs;
      float y = x / (1.f + __expf(-x));  // silu
      ht_sh[(dd * 16 + a) * 40 + nn * 16 + g] = f2bf(y);
    }
  }
  __syncthreads();

#pragma unroll
  for (int r = 0; r < 2; ++r) {
    int q = t + 256 * r;
    int d = q >> 2, part = q & 3;
    float4 v = *reinterpret_cast<const float4*>(&ht_sh[d * 40 + part * 8]);
    *reinterpret_cast<float4*>(
        h_t + ((size_t)b * 128 + d) * 512 + n0 + part * 8) = v;
  }
}

// -------------------------------------------------------------------------
// Kernel 2, round 8: 8 CONTINUOUSLY-STREAMING WAVES PER CU.
// v[b,i,c,d] = sum_j mask[b,i,j]*ev[b,i,j,c]*h[b,j,d].
//
// All of R0-R7 (61-67us) had effective streaming concurrency ~3-4 wave-
// equivalents/CU (16 waves x ~25% duty convoys, or 4 waves x ~70% duty);
// per-CU BW stuck at ~3.3 B/cy. This round raises the product:
//  - 1024 blocks x 128 thr (2 waves). Wave = (b, 16 i, 128 d, 256-j half).
//    4 blocks/CU x 2 waves = 8 waves/CU, ALL streaming continuously.
//  - Hot loop has NO barriers and NO LDS: B-operand h_t read directly
//    from L2-resident global (h_t[b]=128KB, reused by 64 waves); per step
//    (32 j): 16 asm-pinned 16B loads, half-size CONV, 24 MFMA.
//  - Counted FIFO waits (m135 semantics): steady step = vmcnt(16)
//    [retire evmk(r)] -> CONV -> vmcnt(8) [retire bv(r)] -> MFMA ->
//    issue bv(r+1), evmk(r+2). Queue invariant: [evmk(r),bv(r),evmk(r+1)].
//  - j-halves combined via 25KB LDS buffer + ONE tail __syncthreads.
// Grid: (N/16, B) = (32,32), 128 thr. __launch_bounds__(128,2): VGPR<=256.
// -------------------------------------------------------------------------
__global__ __launch_bounds__(128, 2) void cfconv_mfma_kernel(
    const float* __restrict__ ev, const float* __restrict__ mask,
    const unsigned short* __restrict__ h_t, float* __restrict__ out) {
  __shared__ float red[64 * 98];  // wave-1 acc hand-off (stride 98: 2-way max)
  const int t = threadIdx.x;
  const int wv = t >> 6, l = t & 63;
  const int l15 = l & 15, quad = l >> 4;
  const int b = blockIdx.y;
  const int i0 = blockIdx.x * 16;
  const int ig = i0 + l15;        // this lane's i row (A operand row)
  const int j0 = wv * 256;        // this wave's j-half

  // ---- per-lane byte bases ----
  // ev[b,i,j,c] fp32: row (b,i) stride 6144B; lane j-base j0+quad*8
  const char* evby = (const char*)ev +
      (size_t)(b * N_ + ig) * 6144 + (size_t)(j0 + quad * 8) * 12;
  const char* mby = (const char*)mask +
      (size_t)(b * N_ + ig) * 2048 + (size_t)(j0 + quad * 8) * 4;
  // h_t[b][d][j] bf16: d-row stride 1024B; 8 nt pointers (d = nt*16+l15)
  const char* hby[8];
#pragma unroll
  for (int nt = 0; nt < 8; ++nt)
    hby[nt] = (const char*)h_t +
        ((size_t)b * 65536 + (size_t)(nt * 16 + l15) * 512 +
         (size_t)(j0 + quad * 8)) * 2;

  f32x4 acc[3][8];
#pragma unroll
  for (int c = 0; c < 3; ++c)
#pragma unroll
    for (int nt = 0; nt < 8; ++nt)
#pragma unroll
      for (int e = 0; e < 4; ++e) acc[c][nt][e] = 0.f;

  // pinned prefetch registers
  f32x4 evA[6], mkA[2], evB[6], mkB[2];  // ev/mask distance-2 (A/B sets)
  short8 bv[8];                          // h_t distance-1
  short8 av[3];

#define SB() __builtin_amdgcn_sched_barrier(0)
#define ALOADF(DST, PTR, OFF)                                  \
  asm volatile("global_load_dwordx4 %0, %1, off offset:" OFF   \
               : "=v"(DST) : "v"(PTR))

// 8 loads: 6x16B ev (96B contiguous: 8 j x 3 c) + 2x16B mask (8 j)
#define ISSUE_EVMK(EVX, MKX, R)                                \
  do {                                                         \
    const char* e_ = evby + (R) * 384;                         \
    const char* m_ = mby + (R) * 128;                          \
    ALOADF(EVX[0], e_, "0");  ALOADF(EVX[1], e_, "16");        \
    ALOADF(EVX[2], e_, "32"); ALOADF(EVX[3], e_, "48");        \
    ALOADF(EVX[4], e_, "64"); ALOADF(EVX[5], e_, "80");        \
    ALOADF(MKX[0], m_, "0");  ALOADF(MKX[1], m_, "16");        \
  } while (0)

// 8 loads: one 16B B-fragment per nt (16 d x 8 j each)
#define ISSUE_BV(R)                                            \
  do {                                                         \
    _Pragma("unroll") for (int nt_ = 0; nt_ < 8; ++nt_) {      \
      const char* h_ = hby[nt_] + (R) * 64;                    \
      ALOADF(bv[nt_], h_, "0");                                \
    }                                                          \
  } while (0)

#define VMW(n)                                       \
  do {                                               \
    asm volatile("s_waitcnt vmcnt(" #n ")");         \
    __builtin_amdgcn_sched_barrier(0);               \
  } while (0)

// av[c] = bf16(ev*mask) for this step's 8 j (k = quad*8+e)
#define CONV(EVX, MKX)                                         \
  do {                                                         \
    _Pragma("unroll") for (int c_ = 0; c_ < 3; ++c_) {         \
      short8 a_;                                               \
      _Pragma("unroll") for (int e_ = 0; e_ < 8; ++e_) {       \
        float mv_ = MKX[e_ >> 2][e_ & 3];                      \
        int f_ = e_ * 3 + c_;                                  \
        a_[e_] = (short)f2bf(EVX[f_ >> 2][f_ & 3] * mv_);      \
      }                                                        \
      av[c_] = a_;                                             \
    }                                                          \
  } while (0)

#define COMPUTE()                                              \
  do {                                                         \
    _Pragma("unroll") for (int nt_ = 0; nt_ < 8; ++nt_)        \
        _Pragma("unroll") for (int c_ = 0; c_ < 3; ++c_)       \
            acc[c_][nt_] = __builtin_amdgcn_mfma_f32_16x16x32_bf16( \
                av[c_], bv[nt_], acc[c_][nt_], 0, 0, 0);       \
  } while (0)

// steady step: queue at top = [evmk(R) 8, bv(R) 8, evmk(R+1) 8]
#define STEP(R, N1, N2, EVX, MKX)                              \
  do {                                                         \
    VMW(N1);            /* evmk(R) retired */                  \
    CONV(EVX, MKX);                                            \
    VMW(N2);            /* bv(R) retired  */                   \
    COMPUTE();                                                 \
    SB();                                                      \
    if ((R) < 7) ISSUE_BV((R) + 1);                            \
    if ((R) < 6) ISSUE_EVMK(EVX, MKX, (R) + 2);                \
    SB();                                                      \
  } while (0)

  // ---- prologue (FIFO order matters): evmk(0), bv(0), evmk(1) ----
  ISSUE_EVMK(evA, mkA, 0);
  ISSUE_BV(0);
  ISSUE_EVMK(evB, mkB, 1);

  STEP(0, 16, 8, evA, mkA);
  STEP(1, 16, 8, evB, mkB);
  STEP(2, 16, 8, evA, mkA);
  STEP(3, 16, 8, evB, mkB);
  STEP(4, 16, 8, evA, mkA);
  STEP(5, 16, 8, evB, mkB);
  STEP(6, 16, 8, evA, mkA);   // issues bv(7) only
  STEP(7, 8, 0, evB, mkB);    // drain

#undef STEP
#undef COMPUTE
#undef CONV
#undef VMW
#undef ISSUE_BV
#undef ISSUE_EVMK
#undef ALOADF
#undef SB

  // ---- combine j-halves: wave 1 -> LDS, barrier, wave 0 adds+stores ----
  if (wv == 1) {
#pragma unroll
    for (int c = 0; c < 3; ++c)
#pragma unroll
      for (int nt = 0; nt < 8; ++nt)
        *reinterpret_cast<f32x4*>(&red[l * 98 + (c * 8 + nt) * 4]) =
            acc[c][nt];
  }
  __syncthreads();
  if (wv == 0) {
#pragma unroll
    for (int c = 0; c < 3; ++c) {
#pragma unroll
      for (int nt = 0; nt < 8; ++nt) {
        f32x4 o =
            *reinterpret_cast<const f32x4*>(&red[l * 98 + (c * 8 + nt) * 4]);
#pragma unroll
        for (int r = 0; r < 4; ++r) {
          int i = i0 + quad * 4 + r;
          out[(((size_t)b * N_ + i) * 3 + c) * H_ + nt * 16 + l15] =
              acc[c][nt][r] + o[r];
        }
      }
    }
  }
}

extern "C" void kernel_launch(void* const* d_in, const int* in_sizes, int n_in,
                              void* d_out, int out_size, void* d_ws,
                              size_t ws_size, hipStream_t stream) {
  const float* s = (const float*)d_in[0];
  const float* ev = (const float*)d_in[1];
  const float* mask = (const float*)d_in[2];
  const float* W1 = (const float*)d_in[3];
  const float* b1 = (const float*)d_in[4];
  float* out = (float*)d_out;
  // ws: h_t bf16 [B][128 d][512 n] = 4 MB
  unsigned short* h_t = (unsigned short*)d_ws;

  lin_ln_silu_kernel<<<dim3(N_ / 32, B_), 256, 0, stream>>>(s, W1, b1, h_t);
  cfconv_mfma_kernel<<<dim3(N_ / 16, B_), 128, 0, stream>>>(ev, mask, h_t, out);
}

// Round 9
// 213.935 us; speedup vs baseline: 1.0189x; 1.0189x over previous
//
#include <hip/hip_runtime.h>
#include <hip/hip_bf16.h>

#define B_ 32
#define N_ 512
#define H_ 128

typedef float f32x4 __attribute__((ext_vector_type(4)));
typedef short short8 __attribute__((ext_vector_type(8)));
typedef short short4v __attribute__((ext_vector_type(4)));

static __device__ __forceinline__ float bf2f(unsigned short u) {
  union { unsigned int ui; float f; } x;
  x.ui = ((unsigned int)u) << 16;
  return x.f;
}
static __device__ __forceinline__ unsigned short f2bf(float f) {
  __hip_bfloat16 h = __float2bfloat16(f);
  return *reinterpret_cast<unsigned short*>(&h);
}

// -------------------------------------------------------------------------
// Kernel 1: h[b,n,d] = silu(LN(s[b,n,:] @ W1[d,:] + b1[d]))
// stored TRANSPOSED bf16 into ws:  h_t[b][d][n]
// (unchanged — not the bottleneck per rocprof)
// -------------------------------------------------------------------------
__global__ __launch_bounds__(256) void lin_ln_silu_kernel(
    const float* __restrict__ s, const float* __restrict__ W1,
    const float* __restrict__ b1, unsigned short* __restrict__ h_t) {
  __shared__ float s_sh[32 * 132];            // [n][k] fp32, pad 132
  __shared__ unsigned short w_sh[128 * 132];  // [d][k] bf16, pad 132
  __shared__ unsigned short ht_sh[128 * 40];  // [d][n] bf16, pad 40
  const int t = threadIdx.x;
  const int b = blockIdx.y;
  const int n0 = blockIdx.x * 32;

#pragma unroll
  for (int r = 0; r < 16; ++r) {
    int q = t + 256 * r;
    int d = q >> 5, part = q & 31;
    float4 v = *reinterpret_cast<const float4*>(W1 + d * H_ + part * 4);
    short4v w;
    w.x = (short)f2bf(v.x); w.y = (short)f2bf(v.y);
    w.z = (short)f2bf(v.z); w.w = (short)f2bf(v.w);
    *reinterpret_cast<short4v*>(&w_sh[d * 132 + part * 4]) = w;
  }
#pragma unroll
  for (int r = 0; r < 4; ++r) {
    int q = t + 256 * r;
    int n = q >> 5, part = q & 31;
    float4 v = *reinterpret_cast<const float4*>(
        s + ((size_t)b * N_ + n0 + n) * H_ + part * 4);
    *reinterpret_cast<float4*>(&s_sh[n * 132 + part * 4]) = v;
  }
  __syncthreads();

  const int a = t & 15;
  const int g = t >> 4;
  float acc[2][8];
#pragma unroll
  for (int nn = 0; nn < 2; ++nn)
#pragma unroll
    for (int dd = 0; dd < 8; ++dd) acc[nn][dd] = 0.f;

  float bias[8];
#pragma unroll
  for (int dd = 0; dd < 8; ++dd) bias[dd] = b1[dd * 16 + a];

  for (int k = 0; k < 128; k += 4) {
    float wf[8][4];
#pragma unroll
    for (int dd = 0; dd < 8; ++dd) {
      short4v wv =
          *reinterpret_cast<const short4v*>(&w_sh[(dd * 16 + a) * 132 + k]);
      wf[dd][0] = bf2f((unsigned short)wv.x);
      wf[dd][1] = bf2f((unsigned short)wv.y);
      wf[dd][2] = bf2f((unsigned short)wv.z);
      wf[dd][3] = bf2f((unsigned short)wv.w);
    }
#pragma unroll
    for (int nn = 0; nn < 2; ++nn) {
      float4 sv =
          *reinterpret_cast<const float4*>(&s_sh[(nn * 16 + g) * 132 + k]);
#pragma unroll
      for (int dd = 0; dd < 8; ++dd) {
        acc[nn][dd] += sv.x * wf[dd][0] + sv.y * wf[dd][1] +
                       sv.z * wf[dd][2] + sv.w * wf[dd][3];
      }
    }
  }

#pragma unroll
  for (int nn = 0; nn < 2; ++nn) {
    float s1 = 0.f, s2 = 0.f;
#pragma unroll
    for (int dd = 0; dd < 8; ++dd) {
      float x = acc[nn][dd] + bias[dd];
      acc[nn][dd] = x;
      s1 += x;
      s2 += x * x;
    }
#pragma unroll
    for (int off = 8; off >= 1; off >>= 1) {
      s1 += __shfl_xor(s1, off);
      s2 += __shfl_xor(s2, off);
    }
    float mean = s1 * (1.f / 128.f);
    float var = s2 * (1.f / 128.f) - mean * mean;
    float rs = rsqrtf(var + 1e-5f);
#pragma unroll
    for (int dd = 0; dd < 8; ++dd) {
      float x = (acc[nn][dd] - mean) * rs;
      float y = x / (1.f + __expf(-x));  // silu
      ht_sh[(dd * 16 + a) * 40 + nn * 16 + g] = f2bf(y);
    }
  }
  __syncthreads();

#pragma unroll
  for (int r = 0; r < 2; ++r) {
    int q = t + 256 * r;
    int d = q >> 2, part = q & 3;
    float4 v = *reinterpret_cast<const float4*>(&ht_sh[d * 40 + part * 8]);
    *reinterpret_cast<float4*>(
        h_t + ((size_t)b * 128 + d) * 512 + n0 + part * 8) = v;
  }
}

// -------------------------------------------------------------------------
// Kernel 2, round 9: R7 (barrier-free, h-resident LDS, asm-pinned
// distance-2 ev/mask prefetch) + VECTORIZED EPILOGUE.
//
// Ten structures (R0-R8) all land 61-69us; the invariant across them is
// the wave-VMEM-instruction count (~260-500k/dispatch) against a measured
// chip-wide service rate of ~4-8G wave-vmem-instr/s (m13's 6.3TB/s copy
// runs at the same ~1KB/instr rate). This round cuts count, not bytes:
// the old epilogue was 96 scattered 256-B store-instrs per wave (98k
// total). The wave's 96 acc values in (il*3+c)*128+d order are EXACTLY
// contiguous output order, so: scatter 96 f32 into a per-wave LDS zone
// (hL reused after one barrier — h is dead), lgkmcnt(0), then 24 linear
// dwordx4 stores (1KB/instr, fully coalesced). 98k -> 25k store instrs;
// total ~262k -> ~190k (-28%). Prediction: dur 65 -> ~48 if the
// instr-throughput model is right; if unchanged, model falsified.
// Grid: (N/64, B) = (8,32) = 256 blocks, 256 thr, 1 block/CU.
// -------------------------------------------------------------------------
__global__ __launch_bounds__(256, 1) void cfconv_mfma_kernel(
    const float* __restrict__ ev, const float* __restrict__ mask,
    const unsigned short* __restrict__ h_t, float* __restrict__ out) {
  __shared__ unsigned short hL[128 * 512];  // 128 KiB: h_t[b], swizzled
  const int t = threadIdx.x;
  const int b = blockIdx.y;
  const int i0 = blockIdx.x * 64;
  const int w = t >> 6, l = t & 63;
  const int l15 = l & 15, quad = l >> 4;
  const int ig = i0 + w * 16 + l15;  // this lane's i row (A operand)

  // ---- prologue: stage h_t[b] (128 rows x 1KB) into LDS, swizzled ----
  {
    const unsigned short* hb = h_t + (size_t)b * 65536;
#pragma unroll 4
    for (int r2 = 0; r2 < 32; ++r2) {
      int row = w * 32 + r2;
      float4 v = *reinterpret_cast<const float4*>(hb + row * 512 + l * 8);
      *reinterpret_cast<float4*>(
          &hL[row * 512 + (l >> 3) * 64 + (((l & 7) ^ (row & 7)) * 8)]) = v;
    }
  }
  __syncthreads();

  f32x4 acc[3][8];
#pragma unroll
  for (int mt = 0; mt < 3; ++mt)
#pragma unroll
    for (int nt = 0; nt < 8; ++nt)
#pragma unroll
      for (int e = 0; e < 4; ++e) acc[mt][nt][e] = 0.f;

  // per-lane stream bases: this lane's A-row (i=ig), j base = quad*8
  const float* evrow =
      ev + ((size_t)(b * N_) + ig) * (N_ * 3) + quad * 24;
  const float* mrow = mask + ((size_t)(b * N_) + ig) * N_ + quad * 8;

  // distance-2 prefetch sets (asm-pinned): 12 ev + 4 mask dwordx4 each
  f32x4 evA[12], mkA[4], evB[12], mkB[4];
  short8 av[3][2];

#define ALOADO(DST, PTR, OFF)                                    \
  asm volatile("global_load_dwordx4 %0, %1, off offset:" OFF     \
               : "=v"(DST) : "v"(PTR))

#define ISSUE_SET(EVX, MKX, R)                                   \
  do {                                                           \
    const char* ep_ = (const char*)evrow + (R)*768;              \
    const char* mp_ = (const char*)mrow + (R)*256;               \
    ALOADO(EVX[0], ep_, "0");    ALOADO(EVX[1], ep_, "16");      \
    ALOADO(EVX[2], ep_, "32");   ALOADO(EVX[3], ep_, "48");      \
    ALOADO(EVX[4], ep_, "64");   ALOADO(EVX[5], ep_, "80");      \
    ALOADO(EVX[6], ep_, "384");  ALOADO(EVX[7], ep_, "400");     \
    ALOADO(EVX[8], ep_, "416");  ALOADO(EVX[9], ep_, "432");     \
    ALOADO(EVX[10], ep_, "448"); ALOADO(EVX[11], ep_, "464");    \
    ALOADO(MKX[0], mp_, "0");    ALOADO(MKX[1], mp_, "16");      \
    ALOADO(MKX[2], mp_, "128");  ALOADO(MKX[3], mp_, "144");     \
  } while (0)

#define VMW(n)                                       \
  do {                                               \
    asm volatile("s_waitcnt vmcnt(" #n ")");         \
    __builtin_amdgcn_sched_barrier(0);               \
  } while (0)

#define CONV(EVX, MKX)                                                  \
  do {                                                                  \
    _Pragma("unroll") for (int ks_ = 0; ks_ < 2; ++ks_) {               \
      float p_[8][3];                                                   \
      _Pragma("unroll") for (int e_ = 0; e_ < 8; ++e_) {                \
        float mv_ = MKX[ks_ * 2 + (e_ >> 2)][e_ & 3];                   \
        _Pragma("unroll") for (int c_ = 0; c_ < 3; ++c_) {              \
          int f_ = e_ * 3 + c_;                                         \
          p_[e_][c_] = EVX[ks_ * 6 + (f_ >> 2)][f_ & 3] * mv_;          \
        }                                                               \
      }                                                                 \
      _Pragma("unroll") for (int c_ = 0; c_ < 3; ++c_) {                \
        short8 a_;                                                      \
        _Pragma("unroll") for (int e_ = 0; e_ < 8; ++e_)                \
            a_[e_] = (short)f2bf(p_[e_][c_]);                           \
        av[c_][ks_] = a_;                                               \
      }                                                                 \
    }                                                                   \
  } while (0)

#define COMPUTE(J0)                                                     \
  do {                                                                  \
    _Pragma("unroll") for (int ks_ = 0; ks_ < 2; ++ks_) {               \
      _Pragma("unroll") for (int nt_ = 0; nt_ < 8; ++nt_) {             \
        int d_ = nt_ * 16 + l15;                                        \
        short8 bv_ = *reinterpret_cast<const short8*>(                  \
            &hL[d_ * 512 + (J0) +                                       \
                (((ks_ * 4 + quad) ^ (l15 & 7)) * 8)]);                 \
        _Pragma("unroll") for (int mt_ = 0; mt_ < 3; ++mt_)             \
            acc[mt_][nt_] = __builtin_amdgcn_mfma_f32_16x16x32_bf16(    \
                av[mt_][ks_], bv_, acc[mt_][nt_], 0, 0, 0);             \
      }                                                                 \
    }                                                                   \
  } while (0)

  // ---- free-running pipeline: no barriers, counted waits only ----
  ISSUE_SET(evA, mkA, 0);
  ISSUE_SET(evB, mkB, 1);

  VMW(16); CONV(evA, mkA); ISSUE_SET(evA, mkA, 2); COMPUTE(0);
  VMW(16); CONV(evB, mkB); ISSUE_SET(evB, mkB, 3); COMPUTE(64);
  VMW(16); CONV(evA, mkA); ISSUE_SET(evA, mkA, 4); COMPUTE(128);
  VMW(16); CONV(evB, mkB); ISSUE_SET(evB, mkB, 5); COMPUTE(192);
  VMW(16); CONV(evA, mkA); ISSUE_SET(evA, mkA, 6); COMPUTE(256);
  VMW(16); CONV(evB, mkB); ISSUE_SET(evB, mkB, 7); COMPUTE(320);
  VMW(16); CONV(evA, mkA); COMPUTE(384);
  VMW(0);  CONV(evB, mkB); COMPUTE(448);

#undef COMPUTE
#undef CONV
#undef VMW
#undef ISSUE_SET
#undef ALOADO

  // ---- epilogue (NEW): vectorized 1-KB stores via LDS re-order ----
  // All waves done reading hL -> reuse it. Wave w owns zone of 6144 f32.
  // LDS offset (il*3+c)*128+d  ==  out offset within the wave's 16-row
  // span: out[((b*512+i0+w*16+il)*3+c)*128+d]. So scatter-write 96 f32,
  // then 24 LINEAR dwordx4 read+store instrs (contiguous 24 KB).
  __syncthreads();  // hL dead for compute; safe to overwrite
  {
    float* zf = reinterpret_cast<float*>(hL) + w * 6144;
#pragma unroll
    for (int c = 0; c < 3; ++c)
#pragma unroll
      for (int nt = 0; nt < 8; ++nt)
#pragma unroll
        for (int r = 0; r < 4; ++r)
          zf[((quad * 4 + r) * 3 + c) * 128 + nt * 16 + l15] = acc[c][nt][r];
    asm volatile("s_waitcnt lgkmcnt(0)");
    __builtin_amdgcn_sched_barrier(0);
    float* ob = out + ((size_t)(b * N_) + i0 + w * 16) * 3 * 128;
#pragma unroll
    for (int k = 0; k < 24; ++k) {
      int flat = k * 256 + l * 4;
      f32x4 v = *reinterpret_cast<const f32x4*>(zf + flat);
      *reinterpret_cast<f32x4*>(ob + flat) = v;
    }
  }
}

extern "C" void kernel_launch(void* const* d_in, const int* in_sizes, int n_in,
                              void* d_out, int out_size, void* d_ws,
                              size_t ws_size, hipStream_t stream) {
  const float* s = (const float*)d_in[0];
  const float* ev = (const float*)d_in[1];
  const float* mask = (const float*)d_in[2];
  const float* W1 = (const float*)d_in[3];
  const float* b1 = (const float*)d_in[4];
  float* out = (float*)d_out;
  // ws: h_t bf16 [B][128 d][512 n] = 4 MB
  unsigned short* h_t = (unsigned short*)d_ws;

  lin_ln_silu_kernel<<<dim3(N_ / 32, B_), 256, 0, stream>>>(s, W1, b1, h_t);
  cfconv_mfma_kernel<<<dim3(N_ / 64, B_), 256, 0, stream>>>(ev, mask, h_t, out);
}

// Round 10
// 203.338 us; speedup vs baseline: 1.0720x; 1.0521x over previous
//
#include <hip/hip_runtime.h>
#include <hip/hip_bf16.h>

#define B_ 32
#define N_ 512
#define H_ 128

typedef float f32x4 __attribute__((ext_vector_type(4)));
typedef short short8 __attribute__((ext_vector_type(8)));
typedef short short4v __attribute__((ext_vector_type(4)));

static __device__ __forceinline__ float bf2f(unsigned short u) {
  union { unsigned int ui; float f; } x;
  x.ui = ((unsigned int)u) << 16;
  return x.f;
}
static __device__ __forceinline__ unsigned short f2bf(float f) {
  __hip_bfloat16 h = __float2bfloat16(f);
  return *reinterpret_cast<unsigned short*>(&h);
}

// -------------------------------------------------------------------------
// Kernel 1, round 10: MFMA rewrite. h[b,n,d] = silu(LN_d(s@W1^T + b1)),
// stored transposed bf16: h_t[b][d][n].
// Old version was a scalar-VALU matmul (no MFMA for a matmul-shaped op —
// Guideline 10 violation) estimated 10-25us; it sits inside the ~146us
// non-cfconv part of the timed region that nine rounds never touched.
// New: per block (32 n x 128 d, K=128): bf16 LDS tiles (pad 136 shorts =
// 17x16B rows -> b128 frag reads 2-way conflict = free), wave w owns
// d in [32w,32w+32): 2 m-tiles x 2 c-tiles x 4 k-slabs = 16 MFMA.
// LN: in-lane ct-sum -> shfl_xor over l15 (16-lane group) -> 1KB LDS
// cross-wave combine -> mean/rsqrt -> silu -> transpose-store via ht_sh.
// Grid: (N/32, B) = (16,32), 256 thr, __launch_bounds__(256,2).
// -------------------------------------------------------------------------
__global__ __launch_bounds__(256, 2) void lin_ln_silu_kernel(
    const float* __restrict__ s, const float* __restrict__ W1,
    const float* __restrict__ b1, unsigned short* __restrict__ h_t) {
  __shared__ unsigned short sA[32 * 136];   // [n][k] bf16, pad 136
  __shared__ unsigned short wB[128 * 136];  // [d][k] bf16, pad 136
  __shared__ unsigned short ht_sh[128 * 40];  // [d][n] bf16, pad 40
  __shared__ float buf[4][32][2];           // per-wave LN partials
  const int t = threadIdx.x;
  const int b = blockIdx.y;
  const int n0 = blockIdx.x * 32;
  const int w = t >> 6, l = t & 63;
  const int l15 = l & 15, quad = l >> 4;

  // ---- stage W1 (128x128 f32 -> bf16), coalesced float4 ----
#pragma unroll
  for (int r = 0; r < 16; ++r) {
    int q = t + 256 * r;
    int d = q >> 5, part = q & 31;
    float4 v = *reinterpret_cast<const float4*>(W1 + d * H_ + part * 4);
    short4v wv;
    wv.x = (short)f2bf(v.x); wv.y = (short)f2bf(v.y);
    wv.z = (short)f2bf(v.z); wv.w = (short)f2bf(v.w);
    *reinterpret_cast<short4v*>(&wB[d * 136 + part * 4]) = wv;
  }
  // ---- stage s tile (32x128 f32 -> bf16) ----
#pragma unroll
  for (int r = 0; r < 4; ++r) {
    int q = t + 256 * r;
    int n = q >> 5, part = q & 31;
    float4 v = *reinterpret_cast<const float4*>(
        s + ((size_t)b * N_ + n0 + n) * H_ + part * 4);
    short4v sv;
    sv.x = (short)f2bf(v.x); sv.y = (short)f2bf(v.y);
    sv.z = (short)f2bf(v.z); sv.w = (short)f2bf(v.w);
    *reinterpret_cast<short4v*>(&sA[n * 136 + part * 4]) = sv;
  }
  __syncthreads();

  // ---- MFMA: acc[mt][ct], n = n0+mt*16+quad*4+reg, d = w*32+ct*16+l15 ----
  f32x4 acc[2][2];
#pragma unroll
  for (int mt = 0; mt < 2; ++mt)
#pragma unroll
    for (int ct = 0; ct < 2; ++ct)
#pragma unroll
      for (int e = 0; e < 4; ++e) acc[mt][ct][e] = 0.f;

#pragma unroll
  for (int ks = 0; ks < 4; ++ks) {
    short8 av[2], bv[2];
#pragma unroll
    for (int mt = 0; mt < 2; ++mt)
      av[mt] = *reinterpret_cast<const short8*>(
          &sA[(mt * 16 + l15) * 136 + ks * 32 + quad * 8]);
#pragma unroll
    for (int ct = 0; ct < 2; ++ct)
      bv[ct] = *reinterpret_cast<const short8*>(
          &wB[(w * 32 + ct * 16 + l15) * 136 + ks * 32 + quad * 8]);
#pragma unroll
    for (int mt = 0; mt < 2; ++mt)
#pragma unroll
      for (int ct = 0; ct < 2; ++ct)
        acc[mt][ct] = __builtin_amdgcn_mfma_f32_16x16x32_bf16(
            av[mt], bv[ct], acc[mt][ct], 0, 0, 0);
  }

  // ---- bias ----
  const float bb[2] = {b1[w * 32 + l15], b1[w * 32 + 16 + l15]};
#pragma unroll
  for (int mt = 0; mt < 2; ++mt)
#pragma unroll
    for (int ct = 0; ct < 2; ++ct)
#pragma unroll
      for (int e = 0; e < 4; ++e) acc[mt][ct][e] += bb[ct];

  // ---- LN partials: per (mt,r) row, sum over this wave's 32 d ----
  float s1[2][4], s2[2][4];
#pragma unroll
  for (int mt = 0; mt < 2; ++mt)
#pragma unroll
    for (int r = 0; r < 4; ++r) {
      float x0 = acc[mt][0][r], x1 = acc[mt][1][r];
      s1[mt][r] = x0 + x1;
      s2[mt][r] = x0 * x0 + x1 * x1;
    }
#pragma unroll
  for (int off = 1; off <= 8; off <<= 1) {
#pragma unroll
    for (int mt = 0; mt < 2; ++mt)
#pragma unroll
      for (int r = 0; r < 4; ++r) {
        s1[mt][r] += __shfl_xor(s1[mt][r], off);
        s2[mt][r] += __shfl_xor(s2[mt][r], off);
      }
  }
  if (l15 == 0) {
#pragma unroll
    for (int mt = 0; mt < 2; ++mt)
#pragma unroll
      for (int r = 0; r < 4; ++r) {
        int row = mt * 16 + quad * 4 + r;
        buf[w][row][0] = s1[mt][r];
        buf[w][row][1] = s2[mt][r];
      }
  }
  __syncthreads();

  // ---- finish LN + SiLU + transpose into ht_sh ----
#pragma unroll
  for (int mt = 0; mt < 2; ++mt)
#pragma unroll
    for (int r = 0; r < 4; ++r) {
      int row = mt * 16 + quad * 4 + r;
      float S1 = buf[0][row][0] + buf[1][row][0] + buf[2][row][0] +
                 buf[3][row][0];
      float S2 = buf[0][row][1] + buf[1][row][1] + buf[2][row][1] +
                 buf[3][row][1];
      float mean = S1 * (1.f / 128.f);
      float var = S2 * (1.f / 128.f) - mean * mean;
      float rs = rsqrtf(var + 1e-5f);
#pragma unroll
      for (int ct = 0; ct < 2; ++ct) {
        float x = (acc[mt][ct][r] - mean) * rs;
        float y = x / (1.f + __expf(-x));  // silu
        ht_sh[(w * 32 + ct * 16 + l15) * 40 + row] = f2bf(y);
      }
    }
  __syncthreads();

  // ---- coalesced copy-out: 128 d-rows x 32 n (64 B/row) ----
#pragma unroll
  for (int r = 0; r < 2; ++r) {
    int q = t + 256 * r;
    int d = q >> 2, part = q & 3;
    float4 v = *reinterpret_cast<const float4*>(&ht_sh[d * 40 + part * 8]);
    *reinterpret_cast<float4*>(
        h_t + ((size_t)b * 128 + d) * 512 + n0 + part * 8) = v;
  }
}

// -------------------------------------------------------------------------
// Kernel 2: UNCHANGED from round 9 (the control: barrier-free, h-resident
// LDS, asm-pinned distance-2 ev/mask prefetch, vectorized epilogue).
// Eleven structural variants land 62-69us; this one is the current best
// and passes. Its counters this round must be unchanged.
// Grid: (N/64, B) = (8,32) = 256 blocks, 256 thr, 1 block/CU.
// -------------------------------------------------------------------------
__global__ __launch_bounds__(256, 1) void cfconv_mfma_kernel(
    const float* __restrict__ ev, const float* __restrict__ mask,
    const unsigned short* __restrict__ h_t, float* __restrict__ out) {
  __shared__ unsigned short hL[128 * 512];  // 128 KiB: h_t[b], swizzled
  const int t = threadIdx.x;
  const int b = blockIdx.y;
  const int i0 = blockIdx.x * 64;
  const int w = t >> 6, l = t & 63;
  const int l15 = l & 15, quad = l >> 4;
  const int ig = i0 + w * 16 + l15;  // this lane's i row (A operand)

  // ---- prologue: stage h_t[b] (128 rows x 1KB) into LDS, swizzled ----
  {
    const unsigned short* hb = h_t + (size_t)b * 65536;
#pragma unroll 4
    for (int r2 = 0; r2 < 32; ++r2) {
      int row = w * 32 + r2;
      float4 v = *reinterpret_cast<const float4*>(hb + row * 512 + l * 8);
      *reinterpret_cast<float4*>(
          &hL[row * 512 + (l >> 3) * 64 + (((l & 7) ^ (row & 7)) * 8)]) = v;
    }
  }
  __syncthreads();

  f32x4 acc[3][8];
#pragma unroll
  for (int mt = 0; mt < 3; ++mt)
#pragma unroll
    for (int nt = 0; nt < 8; ++nt)
#pragma unroll
      for (int e = 0; e < 4; ++e) acc[mt][nt][e] = 0.f;

  const float* evrow =
      ev + ((size_t)(b * N_) + ig) * (N_ * 3) + quad * 24;
  const float* mrow = mask + ((size_t)(b * N_) + ig) * N_ + quad * 8;

  f32x4 evA[12], mkA[4], evB[12], mkB[4];
  short8 av[3][2];

#define ALOADO(DST, PTR, OFF)                                    \
  asm volatile("global_load_dwordx4 %0, %1, off offset:" OFF     \
               : "=v"(DST) : "v"(PTR))

#define ISSUE_SET(EVX, MKX, R)                                   \
  do {                                                           \
    const char* ep_ = (const char*)evrow + (R)*768;              \
    const char* mp_ = (const char*)mrow + (R)*256;               \
    ALOADO(EVX[0], ep_, "0");    ALOADO(EVX[1], ep_, "16");      \
    ALOADO(EVX[2], ep_, "32");   ALOADO(EVX[3], ep_, "48");      \
    ALOADO(EVX[4], ep_, "64");   ALOADO(EVX[5], ep_, "80");      \
    ALOADO(EVX[6], ep_, "384");  ALOADO(EVX[7], ep_, "400");     \
    ALOADO(EVX[8], ep_, "416");  ALOADO(EVX[9], ep_, "432");     \
    ALOADO(EVX[10], ep_, "448"); ALOADO(EVX[11], ep_, "464");    \
    ALOADO(MKX[0], mp_, "0");    ALOADO(MKX[1], mp_, "16");      \
    ALOADO(MKX[2], mp_, "128");  ALOADO(MKX[3], mp_, "144");     \
  } while (0)

#define VMW(n)                                       \
  do {                                               \
    asm volatile("s_waitcnt vmcnt(" #n ")");         \
    __builtin_amdgcn_sched_barrier(0);               \
  } while (0)

#define CONV(EVX, MKX)                                                  \
  do {                                                                  \
    _Pragma("unroll") for (int ks_ = 0; ks_ < 2; ++ks_) {               \
      float p_[8][3];                                                   \
      _Pragma("unroll") for (int e_ = 0; e_ < 8; ++e_) {                \
        float mv_ = MKX[ks_ * 2 + (e_ >> 2)][e_ & 3];                   \
        _Pragma("unroll") for (int c_ = 0; c_ < 3; ++c_) {              \
          int f_ = e_ * 3 + c_;                                         \
          p_[e_][c_] = EVX[ks_ * 6 + (f_ >> 2)][f_ & 3] * mv_;          \
        }                                                               \
      }                                                                 \
      _Pragma("unroll") for (int c_ = 0; c_ < 3; ++c_) {                \
        short8 a_;                                                      \
        _Pragma("unroll") for (int e_ = 0; e_ < 8; ++e_)                \
            a_[e_] = (short)f2bf(p_[e_][c_]);                           \
        av[c_][ks_] = a_;                                               \
      }                                                                 \
    }                                                                   \
  } while (0)

#define COMPUTE(J0)                                                     \
  do {                                                                  \
    _Pragma("unroll") for (int ks_ = 0; ks_ < 2; ++ks_) {               \
      _Pragma("unroll") for (int nt_ = 0; nt_ < 8; ++nt_) {             \
        int d_ = nt_ * 16 + l15;                                        \
        short8 bv_ = *reinterpret_cast<const short8*>(                  \
            &hL[d_ * 512 + (J0) +                                       \
                (((ks_ * 4 + quad) ^ (l15 & 7)) * 8)]);                 \
        _Pragma("unroll") for (int mt_ = 0; mt_ < 3; ++mt_)             \
            acc[mt_][nt_] = __builtin_amdgcn_mfma_f32_16x16x32_bf16(    \
                av[mt_][ks_], bv_, acc[mt_][nt_], 0, 0, 0);             \
      }                                                                 \
    }                                                                   \
  } while (0)

  // ---- free-running pipeline: no barriers, counted waits only ----
  ISSUE_SET(evA, mkA, 0);
  ISSUE_SET(evB, mkB, 1);

  VMW(16); CONV(evA, mkA); ISSUE_SET(evA, mkA, 2); COMPUTE(0);
  VMW(16); CONV(evB, mkB); ISSUE_SET(evB, mkB, 3); COMPUTE(64);
  VMW(16); CONV(evA, mkA); ISSUE_SET(evA, mkA, 4); COMPUTE(128);
  VMW(16); CONV(evB, mkB); ISSUE_SET(evB, mkB, 5); COMPUTE(192);
  VMW(16); CONV(evA, mkA); ISSUE_SET(evA, mkA, 6); COMPUTE(256);
  VMW(16); CONV(evB, mkB); ISSUE_SET(evB, mkB, 7); COMPUTE(320);
  VMW(16); CONV(evA, mkA); COMPUTE(384);
  VMW(0);  CONV(evB, mkB); COMPUTE(448);

#undef COMPUTE
#undef CONV
#undef VMW
#undef ISSUE_SET
#undef ALOADO

  // ---- epilogue: vectorized 1-KB stores via LDS re-order ----
  __syncthreads();  // hL dead for compute; safe to overwrite
  {
    float* zf = reinterpret_cast<float*>(hL) + w * 6144;
#pragma unroll
    for (int c = 0; c < 3; ++c)
#pragma unroll
      for (int nt = 0; nt < 8; ++nt)
#pragma unroll
        for (int r = 0; r < 4; ++r)
          zf[((quad * 4 + r) * 3 + c) * 128 + nt * 16 + l15] = acc[c][nt][r];
    asm volatile("s_waitcnt lgkmcnt(0)");
    __builtin_amdgcn_sched_barrier(0);
    float* ob = out + ((size_t)(b * N_) + i0 + w * 16) * 3 * 128;
#pragma unroll
    for (int k = 0; k < 24; ++k) {
      int flat = k * 256 + l * 4;
      f32x4 v = *reinterpret_cast<const f32x4*>(zf + flat);
      *reinterpret_cast<f32x4*>(ob + flat) = v;
    }
  }
}

extern "C" void kernel_launch(void* const* d_in, const int* in_sizes, int n_in,
                              void* d_out, int out_size, void* d_ws,
                              size_t ws_size, hipStream_t stream) {
  const float* s = (const float*)d_in[0];
  const float* ev = (const float*)d_in[1];
  const float* mask = (const float*)d_in[2];
  const float* W1 = (const float*)d_in[3];
  const float* b1 = (const float*)d_in[4];
  float* out = (float*)d_out;
  // ws: h_t bf16 [B][128 d][512 n] = 4 MB
  unsigned short* h_t = (unsigned short*)d_ws;

  lin_ln_silu_kernel<<<dim3(N_ / 32, B_), 256, 0, stream>>>(s, W1, b1, h_t);
  cfconv_mfma_kernel<<<dim3(N_ / 64, B_), 256, 0, stream>>>(ev, mask, h_t, out);
}

// Round 12
// 203.234 us; speedup vs baseline: 1.0725x; 1.0005x over previous
//
#include <hip/hip_runtime.h>
#include <hip/hip_bf16.h>

#define B_ 32
#define N_ 512
#define H_ 128

typedef float f32x4 __attribute__((ext_vector_type(4)));
typedef short short8 __attribute__((ext_vector_type(8)));
typedef short short4v __attribute__((ext_vector_type(4)));

static __device__ __forceinline__ float bf2f(unsigned short u) {
  union { unsigned int ui; float f; } x;
  x.ui = ((unsigned int)u) << 16;
  return x.f;
}
static __device__ __forceinline__ unsigned short f2bf(float f) {
  __hip_bfloat16 h = __float2bfloat16(f);
  return *reinterpret_cast<unsigned short*>(&h);
}

// -------------------------------------------------------------------------
// Kernel 1 (round 10 MFMA version, unchanged — passed, bought ~20us):
// h[b,n,d] = silu(LN_d(s@W1^T + b1)), stored transposed bf16 h_t[b][d][n].
// -------------------------------------------------------------------------
__global__ __launch_bounds__(256, 2) void lin_ln_silu_kernel(
    const float* __restrict__ s, const float* __restrict__ W1,
    const float* __restrict__ b1, unsigned short* __restrict__ h_t) {
  __shared__ unsigned short sA[32 * 136];   // [n][k] bf16, pad 136
  __shared__ unsigned short wB[128 * 136];  // [d][k] bf16, pad 136
  __shared__ unsigned short ht_sh[128 * 40];  // [d][n] bf16, pad 40
  __shared__ float buf[4][32][2];           // per-wave LN partials
  const int t = threadIdx.x;
  const int b = blockIdx.y;
  const int n0 = blockIdx.x * 32;
  const int w = t >> 6, l = t & 63;
  const int l15 = l & 15, quad = l >> 4;

#pragma unroll
  for (int r = 0; r < 16; ++r) {
    int q = t + 256 * r;
    int d = q >> 5, part = q & 31;
    float4 v = *reinterpret_cast<const float4*>(W1 + d * H_ + part * 4);
    short4v wv;
    wv.x = (short)f2bf(v.x); wv.y = (short)f2bf(v.y);
    wv.z = (short)f2bf(v.z); wv.w = (short)f2bf(v.w);
    *reinterpret_cast<short4v*>(&wB[d * 136 + part * 4]) = wv;
  }
#pragma unroll
  for (int r = 0; r < 4; ++r) {
    int q = t + 256 * r;
    int n = q >> 5, part = q & 31;
    float4 v = *reinterpret_cast<const float4*>(
        s + ((size_t)b * N_ + n0 + n) * H_ + part * 4);
    short4v sv;
    sv.x = (short)f2bf(v.x); sv.y = (short)f2bf(v.y);
    sv.z = (short)f2bf(v.z); sv.w = (short)f2bf(v.w);
    *reinterpret_cast<short4v*>(&sA[n * 136 + part * 4]) = sv;
  }
  __syncthreads();

  f32x4 acc[2][2];
#pragma unroll
  for (int mt = 0; mt < 2; ++mt)
#pragma unroll
    for (int ct = 0; ct < 2; ++ct)
#pragma unroll
      for (int e = 0; e < 4; ++e) acc[mt][ct][e] = 0.f;

#pragma unroll
  for (int ks = 0; ks < 4; ++ks) {
    short8 av[2], bv[2];
#pragma unroll
    for (int mt = 0; mt < 2; ++mt)
      av[mt] = *reinterpret_cast<const short8*>(
          &sA[(mt * 16 + l15) * 136 + ks * 32 + quad * 8]);
#pragma unroll
    for (int ct = 0; ct < 2; ++ct)
      bv[ct] = *reinterpret_cast<const short8*>(
          &wB[(w * 32 + ct * 16 + l15) * 136 + ks * 32 + quad * 8]);
#pragma unroll
    for (int mt = 0; mt < 2; ++mt)
#pragma unroll
      for (int ct = 0; ct < 2; ++ct)
        acc[mt][ct] = __builtin_amdgcn_mfma_f32_16x16x32_bf16(
            av[mt], bv[ct], acc[mt][ct], 0, 0, 0);
  }

  const float bb[2] = {b1[w * 32 + l15], b1[w * 32 + 16 + l15]};
#pragma unroll
  for (int mt = 0; mt < 2; ++mt)
#pragma unroll
    for (int ct = 0; ct < 2; ++ct)
#pragma unroll
      for (int e = 0; e < 4; ++e) acc[mt][ct][e] += bb[ct];

  float s1[2][4], s2[2][4];
#pragma unroll
  for (int mt = 0; mt < 2; ++mt)
#pragma unroll
    for (int r = 0; r < 4; ++r) {
      float x0 = acc[mt][0][r], x1 = acc[mt][1][r];
      s1[mt][r] = x0 + x1;
      s2[mt][r] = x0 * x0 + x1 * x1;
    }
#pragma unroll
  for (int off = 1; off <= 8; off <<= 1) {
#pragma unroll
    for (int mt = 0; mt < 2; ++mt)
#pragma unroll
      for (int r = 0; r < 4; ++r) {
        s1[mt][r] += __shfl_xor(s1[mt][r], off);
        s2[mt][r] += __shfl_xor(s2[mt][r], off);
      }
  }
  if (l15 == 0) {
#pragma unroll
    for (int mt = 0; mt < 2; ++mt)
#pragma unroll
      for (int r = 0; r < 4; ++r) {
        int row = mt * 16 + quad * 4 + r;
        buf[w][row][0] = s1[mt][r];
        buf[w][row][1] = s2[mt][r];
      }
  }
  __syncthreads();

#pragma unroll
  for (int mt = 0; mt < 2; ++mt)
#pragma unroll
    for (int r = 0; r < 4; ++r) {
      int row = mt * 16 + quad * 4 + r;
      float S1 = buf[0][row][0] + buf[1][row][0] + buf[2][row][0] +
                 buf[3][row][0];
      float S2 = buf[0][row][1] + buf[1][row][1] + buf[2][row][1] +
                 buf[3][row][1];
      float mean = S1 * (1.f / 128.f);
      float var = S2 * (1.f / 128.f) - mean * mean;
      float rs = rsqrtf(var + 1e-5f);
#pragma unroll
      for (int ct = 0; ct < 2; ++ct) {
        float x = (acc[mt][ct][r] - mean) * rs;
        float y = x / (1.f + __expf(-x));  // silu
        ht_sh[(w * 32 + ct * 16 + l15) * 40 + row] = f2bf(y);
      }
    }
  __syncthreads();

#pragma unroll
  for (int r = 0; r < 2; ++r) {
    int q = t + 256 * r;
    int d = q >> 2, part = q & 3;
    float4 v = *reinterpret_cast<const float4*>(&ht_sh[d * 40 + part * 8]);
    *reinterpret_cast<float4*>(
        h_t + ((size_t)b * 128 + d) * 512 + n0 + part * 8) = v;
  }
}

// -------------------------------------------------------------------------
// Kernel 2, round 12: 8 WAVES + SPILL-ROBUST WAITS.
// v[b,i,c,d] = sum_j mask[b,i,j]*ev[b,i,j,c]*h[b,j,d].
//
// R11 (same structure, distance-2) FAILED accuracy: at 512thr = 2 waves/
// SIMD the unified VGPR budget is 256/wave but the kernel needed ~264
// (acc 96 + two prefetch sets 128 + misc 40) -> compiler spilled; scratch
// spills are VMEM ops that increment vmcnt, so the hand-counted vmcnt(16)
// waits returned early -> CONV read stale registers. (R9 passed the same
// math at 1 wave/SIMD = 512-reg budget, no spill.)
// Fix: (1) distance-1 single prefetch set (evv[12]+mkv[4] = 64 regs,
// total ~200 < 256, no spill); (2) ALL waits vmcnt(0) — correct even if
// spill traffic exists. Latency hiding now relies on TLP: 2 waves/SIMD
// cover each other's stalls — exactly the 8-wave hypothesis under test
// (the 6.7TB/s fill kernel pipelines nothing; it just has many waves).
// Grid: (N/64, B) = (8,32) = 256 blocks, 512 thr, 1 block/CU.
// -------------------------------------------------------------------------
__global__ __launch_bounds__(512, 1) void cfconv_mfma_kernel(
    const float* __restrict__ ev, const float* __restrict__ mask,
    const unsigned short* __restrict__ h_t, float* __restrict__ out) {
  __shared__ unsigned short hL[128 * 512];  // 128 KiB: h_t[b], swizzled
  const int t = threadIdx.x;
  const int b = blockIdx.y;
  const int i0 = blockIdx.x * 64;
  const int w = t >> 6, l = t & 63;
  const int g = w & 3, jh = w >> 2;  // i-group, j-half
  const int l15 = l & 15, quad = l >> 4;
  const int ig = i0 + g * 16 + l15;  // this lane's i row (A operand)

  // ---- prologue: stage h_t[b] (128 rows x 1KB) into LDS, swizzled ----
  {
    const unsigned short* hb = h_t + (size_t)b * 65536;
#pragma unroll 4
    for (int r2 = 0; r2 < 16; ++r2) {
      int row = w * 16 + r2;
      float4 v = *reinterpret_cast<const float4*>(hb + row * 512 + l * 8);
      *reinterpret_cast<float4*>(
          &hL[row * 512 + (l >> 3) * 64 + (((l & 7) ^ (row & 7)) * 8)]) = v;
    }
  }
  __syncthreads();

  f32x4 acc[3][8];
#pragma unroll
  for (int mt = 0; mt < 3; ++mt)
#pragma unroll
    for (int nt = 0; nt < 8; ++nt)
#pragma unroll
      for (int e = 0; e < 4; ++e) acc[mt][nt][e] = 0.f;

  // per-lane stream bases: lane's i row + this wave's j-half folded in
  const float* evrow = ev + ((size_t)(b * N_) + ig) * (N_ * 3) +
                       jh * 768 + quad * 24;
  const float* mrow = mask + ((size_t)(b * N_) + ig) * N_ +
                      jh * 256 + quad * 8;
  const int jbase = jh * 256;  // ushort offset into hL rows

  // SINGLE prefetch set (distance-1): 12 ev + 4 mask dwordx4 = 64 VGPRs
  f32x4 evv[12], mkv[4];
  short8 av[3][2];

#define ALOADO(DST, PTR, OFF)                                    \
  asm volatile("global_load_dwordx4 %0, %1, off offset:" OFF     \
               : "=v"(DST) : "v"(PTR))

#define ISSUE_SET(R)                                             \
  do {                                                           \
    const char* ep_ = (const char*)evrow + (R)*768;              \
    const char* mp_ = (const char*)mrow + (R)*256;               \
    ALOADO(evv[0], ep_, "0");    ALOADO(evv[1], ep_, "16");      \
    ALOADO(evv[2], ep_, "32");   ALOADO(evv[3], ep_, "48");      \
    ALOADO(evv[4], ep_, "64");   ALOADO(evv[5], ep_, "80");      \
    ALOADO(evv[6], ep_, "384");  ALOADO(evv[7], ep_, "400");     \
    ALOADO(evv[8], ep_, "416");  ALOADO(evv[9], ep_, "432");     \
    ALOADO(evv[10], ep_, "448"); ALOADO(evv[11], ep_, "464");    \
    ALOADO(mkv[0], mp_, "0");    ALOADO(mkv[1], mp_, "16");      \
    ALOADO(mkv[2], mp_, "128");  ALOADO(mkv[3], mp_, "144");     \
  } while (0)

// spill-robust full drain: correct regardless of any scratch traffic
#define VMW0()                                       \
  do {                                               \
    asm volatile("s_waitcnt vmcnt(0)");              \
    __builtin_amdgcn_sched_barrier(0);               \
  } while (0)

#define CONV()                                                          \
  do {                                                                  \
    _Pragma("unroll") for (int ks_ = 0; ks_ < 2; ++ks_) {               \
      float p_[8][3];                                                   \
      _Pragma("unroll") for (int e_ = 0; e_ < 8; ++e_) {                \
        float mv_ = mkv[ks_ * 2 + (e_ >> 2)][e_ & 3];                   \
        _Pragma("unroll") for (int c_ = 0; c_ < 3; ++c_) {              \
          int f_ = e_ * 3 + c_;                                         \
          p_[e_][c_] = evv[ks_ * 6 + (f_ >> 2)][f_ & 3] * mv_;          \
        }                                                               \
      }                                                                 \
      _Pragma("unroll") for (int c_ = 0; c_ < 3; ++c_) {                \
        short8 a_;                                                      \
        _Pragma("unroll") for (int e_ = 0; e_ < 8; ++e_)                \
            a_[e_] = (short)f2bf(p_[e_][c_]);                           \
        av[c_][ks_] = a_;                                               \
      }                                                                 \
    }                                                                   \
  } while (0)

#define COMPUTE(J0)                                                     \
  do {                                                                  \
    _Pragma("unroll") for (int ks_ = 0; ks_ < 2; ++ks_) {               \
      _Pragma("unroll") for (int nt_ = 0; nt_ < 8; ++nt_) {             \
        int d_ = nt_ * 16 + l15;                                        \
        short8 bv_ = *reinterpret_cast<const short8*>(                  \
            &hL[d_ * 512 + (J0) +                                       \
                (((ks_ * 4 + quad) ^ (l15 & 7)) * 8)]);                 \
        _Pragma("unroll") for (int mt_ = 0; mt_ < 3; ++mt_)             \
            acc[mt_][nt_] = __builtin_amdgcn_mfma_f32_16x16x32_bf16(    \
                av[mt_][ks_], bv_, acc[mt_][nt_], 0, 0, 0);             \
      }                                                                 \
    }                                                                   \
  } while (0)

  // ---- free-running loop: 4 steps, no barriers, vmcnt(0) waits ----
  ISSUE_SET(0);
  VMW0(); CONV(); ISSUE_SET(1); COMPUTE(jbase + 0);
  VMW0(); CONV(); ISSUE_SET(2); COMPUTE(jbase + 64);
  VMW0(); CONV(); ISSUE_SET(3); COMPUTE(jbase + 128);
  VMW0(); CONV(); COMPUTE(jbase + 192);

#undef COMPUTE
#undef CONV
#undef VMW0
#undef ISSUE_SET
#undef ALOADO

  // ---- combine j-halves + vectorized epilogue (reuse hL) ----
  // zone(g) = 6144 f32; LDS offset (il*3+c)*128+d == contiguous out order.
  __syncthreads();  // all waves done reading hL
  float* zf = reinterpret_cast<float*>(hL) + g * 6144;
  if (jh == 1) {
#pragma unroll
    for (int c = 0; c < 3; ++c)
#pragma unroll
      for (int nt = 0; nt < 8; ++nt)
#pragma unroll
        for (int r = 0; r < 4; ++r)
          zf[((quad * 4 + r) * 3 + c) * 128 + nt * 16 + l15] = acc[c][nt][r];
  }
  __syncthreads();  // jh=1 partials visible
  if (jh == 0) {
#pragma unroll
    for (int c = 0; c < 3; ++c)
#pragma unroll
      for (int nt = 0; nt < 8; ++nt)
#pragma unroll
        for (int r = 0; r < 4; ++r) {
          int idx = ((quad * 4 + r) * 3 + c) * 128 + nt * 16 + l15;
          zf[idx] += acc[c][nt][r];
        }
    asm volatile("s_waitcnt lgkmcnt(0)");
    __builtin_amdgcn_sched_barrier(0);
    float* ob = out + ((size_t)(b * N_) + i0 + g * 16) * 3 * 128;
#pragma unroll
    for (int k = 0; k < 24; ++k) {
      int flat = k * 256 + l * 4;
      f32x4 v = *reinterpret_cast<const f32x4*>(zf + flat);
      *reinterpret_cast<f32x4*>(ob + flat) = v;
    }
  }
}

extern "C" void kernel_launch(void* const* d_in, const int* in_sizes, int n_in,
                              void* d_out, int out_size, void* d_ws,
                              size_t ws_size, hipStream_t stream) {
  const float* s = (const float*)d_in[0];
  const float* ev = (const float*)d_in[1];
  const float* mask = (const float*)d_in[2];
  const float* W1 = (const float*)d_in[3];
  const float* b1 = (const float*)d_in[4];
  float* out = (float*)d_out;
  // ws: h_t bf16 [B][128 d][512 n] = 4 MB
  unsigned short* h_t = (unsigned short*)d_ws;

  lin_ln_silu_kernel<<<dim3(N_ / 32, B_), 256, 0, stream>>>(s, W1, b1, h_t);
  cfconv_mfma_kernel<<<dim3(N_ / 64, B_), 512, 0, stream>>>(ev, mask, h_t, out);
}